// Round 15
// baseline (30.974 us; speedup 1.0000x reference)
//
#include <hip/hip_runtime.h>

// DLGN_VT v13 — fused, occupancy-doubled (i-split across a 512-thread block):
//   512 blocks x 512 thr, 8 rows/block, launch_bounds(512,4) -> 4 waves/SIMD.
//   Thread t: ih = t>>8 (i-half), tl = t&255, fl = tl>>3, kc = tl&7.
//   Phase 1: (fl,kc) holds W1/2/3[fl][16kc..+15] in 48 regs; x kc-skewed in LDS;
//     ih-half computes rows ih*4..ih*4+3 (4 x 48 FMA); combine k-eighths with
//     DPP xor1/xor2 + shfl xor4; writer kc==rr -> Gs[ih*4+rr][32m+fl].
//   V: thread holds v[16] = V[i][j][4c2..], i in [16ih,16ih+16) (coalesced, disjoint).
//   Phase 2: per b: ONE b32 ga = Gs[b][lane&31]; g1 = readlane(ga, 16ih+il) (uniform
//     lane idx); 64 FMA i-first u4; g2/g3 from Gs; p8[b] in regs.
//   Reduce: p8 -> Plds (stride 10), barrier, 8 reads + 6-level shfl -> out.
// No atomics, no memset, no global scratch.

#define BETA 30.0f

// quad_perm DPP: full row/bank mask, bound_ctrl=1 -> old-value-independent
__device__ __forceinline__ float qp_xor1(float a) {   // [1,0,3,2] = 0xB1
    return __int_as_float(__builtin_amdgcn_mov_dpp(__float_as_int(a), 0xB1, 0xF, 0xF, true));
}
__device__ __forceinline__ float qp_xor2(float a) {   // [2,3,0,1] = 0x4E
    return __int_as_float(__builtin_amdgcn_mov_dpp(__float_as_int(a), 0x4E, 0xF, 0xF, true));
}

__global__ __launch_bounds__(512, 4) void dlgn_v13_kernel(
    const float* __restrict__ x,
    const float* __restrict__ W1,
    const float* __restrict__ W2,
    const float* __restrict__ W3,
    const float* __restrict__ V,
    float* __restrict__ out)
{
    __shared__ float xlds[8 * 160];   //  5120 B: kc-chunk stride 20 (bank-exact)
    __shared__ float Gs[8][100];      //  3200 B
    __shared__ float Plds[512 * 10];  // 20480 B: per-thread stride 10

    const int t  = threadIdx.x;
    const int ih = t >> 8;           // i-half 0/1, wave-uniform
    const int tl = t & 255;
    const int b0 = blockIdx.x * 8;

    // ---- Stage x tile (first 256 threads): 1 float4 each, coalesced, kc-skewed ----
    if (t < 256) {
        const int r    = t >> 5;
        const int col4 = t & 31;
        const float4 xv = ((const float4*)(x + (size_t)(b0 + r) * 128))[col4];
        const int skc = col4 >> 2, sc = col4 & 3;
        *(float4*)&xlds[r * 160 + skc * 20 + sc * 4] = xv;
    }

    // ---- W chunks -> 48 registers (global, L2-resident; duplicated across ih) ----
    const int fl = tl >> 3;   // feature-lane 0..31
    const int kc = tl & 7;    // k-chunk 0..7
    float4 w1c[4], w2c[4], w3c[4];
    {
        const float4* W1r = (const float4*)(W1 + fl * 128 + kc * 16);
        const float4* W2r = (const float4*)(W2 + fl * 128 + kc * 16);
        const float4* W3r = (const float4*)(W3 + fl * 128 + kc * 16);
#pragma unroll
        for (int c = 0; c < 4; ++c) {
            w1c[c] = W1r[c]; w2c[c] = W2r[c]; w3c[c] = W3r[c];
        }
    }
    __syncthreads();   // xlds ready

    // ---- Phase 1: 4 rows (this ih-half) x 3 matrices, k-eighth partial dots ----
    float acc[3][4];
#pragma unroll
    for (int m = 0; m < 3; ++m)
#pragma unroll
        for (int rr = 0; rr < 4; ++rr) acc[m][rr] = 0.f;

#pragma unroll
    for (int rr = 0; rr < 4; ++rr) {
        const int row = ih * 4 + rr;          // LDS address math only
        float4 xc[4];
#pragma unroll
        for (int c = 0; c < 4; ++c)
            xc[c] = *(const float4*)&xlds[row * 160 + kc * 20 + c * 4];
#pragma unroll
        for (int c = 0; c < 4; ++c) {
            acc[0][rr] = fmaf(w1c[c].x, xc[c].x, acc[0][rr]);
            acc[0][rr] = fmaf(w1c[c].y, xc[c].y, acc[0][rr]);
            acc[0][rr] = fmaf(w1c[c].z, xc[c].z, acc[0][rr]);
            acc[0][rr] = fmaf(w1c[c].w, xc[c].w, acc[0][rr]);
            acc[1][rr] = fmaf(w2c[c].x, xc[c].x, acc[1][rr]);
            acc[1][rr] = fmaf(w2c[c].y, xc[c].y, acc[1][rr]);
            acc[1][rr] = fmaf(w2c[c].z, xc[c].z, acc[1][rr]);
            acc[1][rr] = fmaf(w2c[c].w, xc[c].w, acc[1][rr]);
            acc[2][rr] = fmaf(w3c[c].x, xc[c].x, acc[2][rr]);
            acc[2][rr] = fmaf(w3c[c].y, xc[c].y, acc[2][rr]);
            acc[2][rr] = fmaf(w3c[c].z, xc[c].z, acc[2][rr]);
            acc[2][rr] = fmaf(w3c[c].w, xc[c].w, acc[2][rr]);
        }
    }

    // ---- Issue V loads now (W regs dead): v[16], i = 16*ih + il, coalesced ----
    const float4* V4 = (const float4*)V;   // f4 idx = i*256 + tl
    float4 v[16];
#pragma unroll
    for (int il = 0; il < 16; ++il)
        v[il] = V4[(ih * 16 + il) * 256 + tl];

    // ---- Combine k-eighths (butterfly over kc = lane&7); sigmoid -> Gs ----
#pragma unroll
    for (int m = 0; m < 3; ++m) {
        float sel = 0.f;
#pragma unroll
        for (int rr = 0; rr < 4; ++rr) {
            float a = acc[m][rr];
            a += qp_xor1(a);
            a += qp_xor2(a);
            a += __shfl_xor(a, 4);
            if (kc == rr) sel = a;      // static select chain (kc<4 lanes write)
        }
        if (kc < 4)
            Gs[ih * 4 + kc][32 * m + fl] = 1.0f / (1.0f + __expf(-BETA * sel));
    }
    __syncthreads();

    // ---- Phase 2: thread = (j = tl>>3, c2 = tl&7); g1 via readlane ----
    const int j  = tl >> 3;   // [0,32)
    const int c2 = tl & 7;    // [0,8)

    float p8[8];
#pragma unroll
    for (int b = 0; b < 8; ++b) {
        const float  ga  = Gs[b][t & 31];               // lane l holds g1[b][l&31]
        const float  g2s = Gs[b][32 + j];
        const float4 g3r = *(const float4*)&Gs[b][64 + c2 * 4];

        float ux = 0.f, uy = 0.f, uz = 0.f, uw = 0.f;
#pragma unroll
        for (int il = 0; il < 16; ++il) {
            const float g1i = __int_as_float(
                __builtin_amdgcn_readlane(__float_as_int(ga), ih * 16 + il));
            ux = fmaf(g1i, v[il].x, ux);
            uy = fmaf(g1i, v[il].y, uy);
            uz = fmaf(g1i, v[il].z, uz);
            uw = fmaf(g1i, v[il].w, uw);
        }
        float s = ux * g3r.x;
        s = fmaf(uy, g3r.y, s);
        s = fmaf(uz, g3r.z, s);
        s = fmaf(uw, g3r.w, s);
        p8[b] = s * g2s;
    }

    // ---- Deferred reduction: 2 packed b128 writes, barrier, one final pass ----
    *(float4*)&Plds[t * 10]     = make_float4(p8[0], p8[1], p8[2], p8[3]);
    *(float4*)&Plds[t * 10 + 4] = make_float4(p8[4], p8[5], p8[6], p8[7]);
    __syncthreads();

    {
        const int fb2 = t >> 6;   // b index 0..7
        const int pt  = t & 63;   // partial index (lane)
        float s = 0.f;
#pragma unroll
        for (int s8 = 0; s8 < 8; ++s8)
            s += Plds[(pt + s8 * 64) * 10 + fb2];
        s += __shfl_xor(s, 1);
        s += __shfl_xor(s, 2);
        s += __shfl_xor(s, 4);
        s += __shfl_xor(s, 8);
        s += __shfl_xor(s, 16);
        s += __shfl_xor(s, 32);
        if (pt == 0) out[b0 + fb2] = s;
    }
}

extern "C" void kernel_launch(void* const* d_in, const int* in_sizes, int n_in,
                              void* d_out, int out_size, void* d_ws, size_t ws_size,
                              hipStream_t stream) {
    const float* x  = (const float*)d_in[0];
    const float* W1 = (const float*)d_in[1];
    const float* W2 = (const float*)d_in[2];
    const float* W3 = (const float*)d_in[3];
    const float* V  = (const float*)d_in[4];
    float* out = (float*)d_out;

    dlgn_v13_kernel<<<dim3(512), dim3(512), 0, stream>>>(x, W1, W2, W3, V, out);
}

// Round 16
// 17.653 us; speedup vs baseline: 1.7546x; 1.7546x over previous
//
#include <hip/hip_runtime.h>

// DLGN_VT v14 — v13 structure with corrected __launch_bounds__(512, 2):
//   (v13's (512,4) was interpreted as 4 blocks/CU -> 64-VGPR cap -> catastrophic spill.
//    (512,2) -> 2 blocks/CU, 16 waves/CU, 128-VGPR cap >= ~100 live -> no spill.)
//   512 blocks x 512 thr, 8 rows/block. Thread: ih=t>>8 (i-half), tl=t&255,
//   fl=tl>>3, kc=tl&7.
//   Phase 1: (fl,kc) holds W1/2/3[fl][16kc..+15] in 48 regs; x kc-skewed in LDS;
//     ih-half computes rows ih*4..+3 (4 x 48 FMA); combine k-eighths with DPP
//     xor1/xor2 + shfl xor4; kc<4 lanes write Gs[ih*4+kc][32m+fl].
//   V: thread holds v[16] = V[i][j][4c2..], i in [16ih,16ih+16) (coalesced, disjoint).
//   Phase 2: per b: ONE b32 ga = Gs[b][lane&31]; g1 = readlane(ga, 16ih+il);
//     64 FMA i-first u4; g2/g3 from Gs; p8[b] in regs.
//   Reduce: p8 -> Plds (stride 10), barrier, 8 reads + 6-level shfl -> out.
// No atomics, no memset, no global scratch.

#define BETA 30.0f

// quad_perm DPP: full row/bank mask, bound_ctrl=1 -> old-value-independent
__device__ __forceinline__ float qp_xor1(float a) {   // [1,0,3,2] = 0xB1
    return __int_as_float(__builtin_amdgcn_mov_dpp(__float_as_int(a), 0xB1, 0xF, 0xF, true));
}
__device__ __forceinline__ float qp_xor2(float a) {   // [2,3,0,1] = 0x4E
    return __int_as_float(__builtin_amdgcn_mov_dpp(__float_as_int(a), 0x4E, 0xF, 0xF, true));
}

__global__ __launch_bounds__(512, 2) void dlgn_v14_kernel(
    const float* __restrict__ x,
    const float* __restrict__ W1,
    const float* __restrict__ W2,
    const float* __restrict__ W3,
    const float* __restrict__ V,
    float* __restrict__ out)
{
    __shared__ float xlds[8 * 160];   //  5120 B: kc-chunk stride 20
    __shared__ float Gs[8][100];      //  3200 B
    __shared__ float Plds[512 * 10];  // 20480 B: per-thread stride 10

    const int t  = threadIdx.x;
    const int ih = t >> 8;           // i-half 0/1, wave-uniform
    const int tl = t & 255;
    const int b0 = blockIdx.x * 8;

    // ---- Stage x tile (first 256 threads): 1 float4 each, coalesced, kc-skewed ----
    if (t < 256) {
        const int r    = t >> 5;
        const int col4 = t & 31;
        const float4 xv = ((const float4*)(x + (size_t)(b0 + r) * 128))[col4];
        const int skc = col4 >> 2, sc = col4 & 3;
        *(float4*)&xlds[r * 160 + skc * 20 + sc * 4] = xv;
    }

    // ---- W chunks -> 48 registers (global, L2-resident; duplicated across ih) ----
    const int fl = tl >> 3;   // feature-lane 0..31
    const int kc = tl & 7;    // k-chunk 0..7
    float4 w1c[4], w2c[4], w3c[4];
    {
        const float4* W1r = (const float4*)(W1 + fl * 128 + kc * 16);
        const float4* W2r = (const float4*)(W2 + fl * 128 + kc * 16);
        const float4* W3r = (const float4*)(W3 + fl * 128 + kc * 16);
#pragma unroll
        for (int c = 0; c < 4; ++c) {
            w1c[c] = W1r[c]; w2c[c] = W2r[c]; w3c[c] = W3r[c];
        }
    }
    __syncthreads();   // xlds ready

    // ---- Phase 1: 4 rows (this ih-half) x 3 matrices, k-eighth partial dots ----
    float acc[3][4];
#pragma unroll
    for (int m = 0; m < 3; ++m)
#pragma unroll
        for (int rr = 0; rr < 4; ++rr) acc[m][rr] = 0.f;

#pragma unroll
    for (int rr = 0; rr < 4; ++rr) {
        const int row = ih * 4 + rr;          // LDS address math only
        float4 xc[4];
#pragma unroll
        for (int c = 0; c < 4; ++c)
            xc[c] = *(const float4*)&xlds[row * 160 + kc * 20 + c * 4];
#pragma unroll
        for (int c = 0; c < 4; ++c) {
            acc[0][rr] = fmaf(w1c[c].x, xc[c].x, acc[0][rr]);
            acc[0][rr] = fmaf(w1c[c].y, xc[c].y, acc[0][rr]);
            acc[0][rr] = fmaf(w1c[c].z, xc[c].z, acc[0][rr]);
            acc[0][rr] = fmaf(w1c[c].w, xc[c].w, acc[0][rr]);
            acc[1][rr] = fmaf(w2c[c].x, xc[c].x, acc[1][rr]);
            acc[1][rr] = fmaf(w2c[c].y, xc[c].y, acc[1][rr]);
            acc[1][rr] = fmaf(w2c[c].z, xc[c].z, acc[1][rr]);
            acc[1][rr] = fmaf(w2c[c].w, xc[c].w, acc[1][rr]);
            acc[2][rr] = fmaf(w3c[c].x, xc[c].x, acc[2][rr]);
            acc[2][rr] = fmaf(w3c[c].y, xc[c].y, acc[2][rr]);
            acc[2][rr] = fmaf(w3c[c].z, xc[c].z, acc[2][rr]);
            acc[2][rr] = fmaf(w3c[c].w, xc[c].w, acc[2][rr]);
        }
    }

    // ---- Issue V loads now (W regs dead): v[16], i = 16*ih + il, coalesced ----
    const float4* V4 = (const float4*)V;   // f4 idx = i*256 + tl
    float4 v[16];
#pragma unroll
    for (int il = 0; il < 16; ++il)
        v[il] = V4[(ih * 16 + il) * 256 + tl];

    // ---- Combine k-eighths (butterfly over kc = lane&7); sigmoid -> Gs ----
#pragma unroll
    for (int m = 0; m < 3; ++m) {
        float sel = 0.f;
#pragma unroll
        for (int rr = 0; rr < 4; ++rr) {
            float a = acc[m][rr];
            a += qp_xor1(a);
            a += qp_xor2(a);
            a += __shfl_xor(a, 4);
            if (kc == rr) sel = a;      // static select chain (kc<4 lanes write)
        }
        if (kc < 4)
            Gs[ih * 4 + kc][32 * m + fl] = 1.0f / (1.0f + __expf(-BETA * sel));
    }
    __syncthreads();

    // ---- Phase 2: thread = (j = tl>>3, c2 = tl&7); g1 via readlane ----
    const int j  = tl >> 3;   // [0,32)
    const int c2 = tl & 7;    // [0,8)

    float p8[8];
#pragma unroll
    for (int b = 0; b < 8; ++b) {
        const float  ga  = Gs[b][t & 31];               // lane l holds g1[b][l&31]
        const float  g2s = Gs[b][32 + j];
        const float4 g3r = *(const float4*)&Gs[b][64 + c2 * 4];

        float ux = 0.f, uy = 0.f, uz = 0.f, uw = 0.f;
#pragma unroll
        for (int il = 0; il < 16; ++il) {
            const float g1i = __int_as_float(
                __builtin_amdgcn_readlane(__float_as_int(ga), ih * 16 + il));
            ux = fmaf(g1i, v[il].x, ux);
            uy = fmaf(g1i, v[il].y, uy);
            uz = fmaf(g1i, v[il].z, uz);
            uw = fmaf(g1i, v[il].w, uw);
        }
        float s = ux * g3r.x;
        s = fmaf(uy, g3r.y, s);
        s = fmaf(uz, g3r.z, s);
        s = fmaf(uw, g3r.w, s);
        p8[b] = s * g2s;
    }

    // ---- Deferred reduction: 2 packed b128 writes, barrier, one final pass ----
    *(float4*)&Plds[t * 10]     = make_float4(p8[0], p8[1], p8[2], p8[3]);
    *(float4*)&Plds[t * 10 + 4] = make_float4(p8[4], p8[5], p8[6], p8[7]);
    __syncthreads();

    {
        const int fb2 = t >> 6;   // b index 0..7
        const int pt  = t & 63;   // partial index (lane)
        float s = 0.f;
#pragma unroll
        for (int s8 = 0; s8 < 8; ++s8)
            s += Plds[(pt + s8 * 64) * 10 + fb2];
        s += __shfl_xor(s, 1);
        s += __shfl_xor(s, 2);
        s += __shfl_xor(s, 4);
        s += __shfl_xor(s, 8);
        s += __shfl_xor(s, 16);
        s += __shfl_xor(s, 32);
        if (pt == 0) out[b0 + fb2] = s;
    }
}

extern "C" void kernel_launch(void* const* d_in, const int* in_sizes, int n_in,
                              void* d_out, int out_size, void* d_ws, size_t ws_size,
                              hipStream_t stream) {
    const float* x  = (const float*)d_in[0];
    const float* W1 = (const float*)d_in[1];
    const float* W2 = (const float*)d_in[2];
    const float* W3 = (const float*)d_in[3];
    const float* V  = (const float*)d_in[4];
    float* out = (float*)d_out;

    dlgn_v14_kernel<<<dim3(512), dim3(512), 0, stream>>>(x, W1, W2, W3, V, out);
}

// Round 17
// 14.124 us; speedup vs baseline: 2.1930x; 1.2499x over previous
//
#include <hip/hip_runtime.h>

// DLGN_VT v15 — v12 base + early-V overlap + phase-2 operand prefetch:
//   512 blocks x 256 thr, 8 rows/block, launch_bounds(256,2).
//   Phase 1: thread (fl=t>>3, kc=t&7) holds W1/2/3[fl][16kc..+15] in 48 regs;
//     x kc-skewed in LDS. V loads (32 float4) issued RIGHT AFTER barrier #1 so the
//     L2 drain overlaps phase-1 FMA + combine (v12 issued them after the FMA loop,
//     leaving only the combine to hide them before barrier #2's vmcnt(0) drain).
//     Combine k-eighths with DPP xor1/xor2 + shfl xor4; sigmoid -> Gs[8][100].
//   Phase 2: prefetch ga8/g2/g3 for ALL 8 b in one LDS burst (static indices),
//     then pure-VALU loop: g1 via readlane, i-first u4, p8[b] in regs.
//   Reduce: p8 -> Plds (stride 10), barrier, 8 reads + 5-level shfl -> out.
// No atomics, no memset, no global scratch.

#define BETA 30.0f

__device__ __forceinline__ float f4c(const float4 v, int c) {
    return c == 0 ? v.x : (c == 1 ? v.y : (c == 2 ? v.z : v.w));
}

// quad_perm DPP: full row/bank mask, bound_ctrl=1 -> old-value-independent
__device__ __forceinline__ float qp_xor1(float a) {   // [1,0,3,2] = 0xB1
    return __int_as_float(__builtin_amdgcn_mov_dpp(__float_as_int(a), 0xB1, 0xF, 0xF, true));
}
__device__ __forceinline__ float qp_xor2(float a) {   // [2,3,0,1] = 0x4E
    return __int_as_float(__builtin_amdgcn_mov_dpp(__float_as_int(a), 0x4E, 0xF, 0xF, true));
}

__global__ __launch_bounds__(256, 2) void dlgn_v15_kernel(
    const float* __restrict__ x,
    const float* __restrict__ W1,
    const float* __restrict__ W2,
    const float* __restrict__ W3,
    const float* __restrict__ V,
    float* __restrict__ out)
{
    __shared__ float xlds[8 * 160];   //  5120 B: kc-chunk stride 20
    __shared__ float Gs[8][100];      //  3200 B
    __shared__ float Plds[2560];      // 10240 B: per-thread stride 10

    const int t  = threadIdx.x;
    const int b0 = blockIdx.x * 8;

    // ---- Stage x tile: 1 float4/thread, coalesced; kc-skewed layout ----
    {
        const int r    = t >> 5;
        const int col4 = t & 31;
        const float4 xv = ((const float4*)(x + (size_t)(b0 + r) * 128))[col4];
        const int skc = col4 >> 2, sc = col4 & 3;
        *(float4*)&xlds[r * 160 + skc * 20 + sc * 4] = xv;
    }

    // ---- W chunks -> 48 registers (global, L2-resident) ----
    const int fl = t >> 3;   // feature-lane 0..31
    const int kc = t & 7;    // k-chunk 0..7
    float4 w1c[4], w2c[4], w3c[4];
    {
        const float4* W1r = (const float4*)(W1 + fl * 128 + kc * 16);
        const float4* W2r = (const float4*)(W2 + fl * 128 + kc * 16);
        const float4* W3r = (const float4*)(W3 + fl * 128 + kc * 16);
#pragma unroll
        for (int c = 0; c < 4; ++c) {
            w1c[c] = W1r[c]; w2c[c] = W2r[c]; w3c[c] = W3r[c];
        }
    }
    __syncthreads();   // xlds ready (drains x/W loads too — they're needed now anyway)

    // ---- Issue V loads NOW: drain overlaps phase-1 FMA + combine ----
    const float4* V4 = (const float4*)V;   // f4 idx = i*256 + t
    float4 v[32];
#pragma unroll
    for (int i = 0; i < 32; ++i) v[i] = V4[i * 256 + t];

    // ---- Phase 1: 8 rows x 3 matrices, k-eighth partial dots ----
    float acc[3][8];
#pragma unroll
    for (int m = 0; m < 3; ++m)
#pragma unroll
        for (int r = 0; r < 8; ++r) acc[m][r] = 0.f;

#pragma unroll
    for (int r = 0; r < 8; ++r) {
        float4 xc[4];
#pragma unroll
        for (int c = 0; c < 4; ++c)
            xc[c] = *(const float4*)&xlds[r * 160 + kc * 20 + c * 4];
#pragma unroll
        for (int c = 0; c < 4; ++c) {
            acc[0][r] = fmaf(w1c[c].x, xc[c].x, acc[0][r]);
            acc[0][r] = fmaf(w1c[c].y, xc[c].y, acc[0][r]);
            acc[0][r] = fmaf(w1c[c].z, xc[c].z, acc[0][r]);
            acc[0][r] = fmaf(w1c[c].w, xc[c].w, acc[0][r]);
            acc[1][r] = fmaf(w2c[c].x, xc[c].x, acc[1][r]);
            acc[1][r] = fmaf(w2c[c].y, xc[c].y, acc[1][r]);
            acc[1][r] = fmaf(w2c[c].z, xc[c].z, acc[1][r]);
            acc[1][r] = fmaf(w2c[c].w, xc[c].w, acc[1][r]);
            acc[2][r] = fmaf(w3c[c].x, xc[c].x, acc[2][r]);
            acc[2][r] = fmaf(w3c[c].y, xc[c].y, acc[2][r]);
            acc[2][r] = fmaf(w3c[c].z, xc[c].z, acc[2][r]);
            acc[2][r] = fmaf(w3c[c].w, xc[c].w, acc[2][r]);
        }
    }

    // ---- Combine k-eighths: DPP xor1/xor2 + shfl xor4; sigmoid -> Gs ----
#pragma unroll
    for (int m = 0; m < 3; ++m) {
        float sel = 0.f;
#pragma unroll
        for (int r = 0; r < 8; ++r) {
            float a = acc[m][r];
            a += qp_xor1(a);
            a += qp_xor2(a);
            a += __shfl_xor(a, 4);
            if (kc == r) sel = a;      // static select chain
        }
        Gs[kc][32 * m + fl] = 1.0f / (1.0f + __expf(-BETA * sel));
    }
    __syncthreads();

    // ---- Phase 2: prefetch ALL Gs operands, then pure-VALU b-loop ----
    const int j  = t >> 3;   // [0,32)
    const int c2 = t & 7;    // [0,8)

    float  ga8[8], g2v[8];
    float4 g3v[8];
#pragma unroll
    for (int b = 0; b < 8; ++b) {
        ga8[b] = Gs[b][t & 31];                        // lane l holds g1[b][l&31]
        g2v[b] = Gs[b][32 + j];
        g3v[b] = *(const float4*)&Gs[b][64 + c2 * 4];
    }

    float p8[8];
#pragma unroll
    for (int b = 0; b < 8; ++b) {
        float ux = 0.f, uy = 0.f, uz = 0.f, uw = 0.f;
#pragma unroll
        for (int i = 0; i < 32; ++i) {
            const float g1i = __int_as_float(
                __builtin_amdgcn_readlane(__float_as_int(ga8[b]), i));   // SGPR
            ux = fmaf(g1i, v[i].x, ux);
            uy = fmaf(g1i, v[i].y, uy);
            uz = fmaf(g1i, v[i].z, uz);
            uw = fmaf(g1i, v[i].w, uw);
        }
        float s = ux * g3v[b].x;
        s = fmaf(uy, g3v[b].y, s);
        s = fmaf(uz, g3v[b].z, s);
        s = fmaf(uw, g3v[b].w, s);
        p8[b] = s * g2v[b];
    }

    // ---- Deferred reduction: 2 packed b128 writes, barrier, one final pass ----
    *(float4*)&Plds[t * 10]     = make_float4(p8[0], p8[1], p8[2], p8[3]);
    *(float4*)&Plds[t * 10 + 4] = make_float4(p8[4], p8[5], p8[6], p8[7]);
    __syncthreads();

    {
        const int fb2 = t >> 5;   // b index 0..7
        const int pt  = t & 31;   // partial index
        float s = 0.f;
#pragma unroll
        for (int s8 = 0; s8 < 8; ++s8)
            s += Plds[(pt + s8 * 32) * 10 + fb2];
        s += __shfl_xor(s, 1);
        s += __shfl_xor(s, 2);
        s += __shfl_xor(s, 4);
        s += __shfl_xor(s, 8);
        s += __shfl_xor(s, 16);
        if (pt == 0) out[b0 + fb2] = s;
    }
}

extern "C" void kernel_launch(void* const* d_in, const int* in_sizes, int n_in,
                              void* d_out, int out_size, void* d_ws, size_t ws_size,
                              hipStream_t stream) {
    const float* x  = (const float*)d_in[0];
    const float* W1 = (const float*)d_in[1];
    const float* W2 = (const float*)d_in[2];
    const float* W3 = (const float*)d_in[3];
    const float* V  = (const float*)d_in[4];
    float* out = (float*)d_out;

    dlgn_v15_kernel<<<dim3(512), dim3(256), 0, stream>>>(x, W1, W2, W3, V, out);
}

// Round 18
// 13.489 us; speedup vs baseline: 2.2962x; 1.0471x over previous
//
#include <hip/hip_runtime.h>

// DLGN_VT v16 — v12 base + v_pk_fma_f32 packing (halve VALU-issue in both FMA loops):
//   512 blocks x 256 thr, 8 rows/block, launch_bounds(256,2). LDS 18.6 KB.
//   Phase 1: thread (fl=t>>3, kc=t&7) holds W1/2/3[fl][16kc..+15] in 48 regs;
//     x kc-skewed in LDS; 8 rows x (24 pk-FMA) via float2 ext-vectors;
//     horizontal add -> combine k-eighths with DPP xor1/xor2 + shfl xor4;
//     sigmoid -> Gs[8][100].
//   V loads issued after phase-1 FMA (v12 ordering — v15 early-issue was neutral).
//   Phase 2: per b: ga b32 read, g1 = readlane; 64 pk-FMA i-first (u2a,u2b);
//     dot with g3, scale by g2; p8[b] in regs.
//   Reduce: p8 -> Plds (stride 10), barrier, 8 reads + 5-level shfl -> out.
// No atomics, no memset, no global scratch.

#define BETA 30.0f

typedef float v2f __attribute__((ext_vector_type(2)));

// quad_perm DPP: full row/bank mask, bound_ctrl=1 -> old-value-independent
__device__ __forceinline__ float qp_xor1(float a) {   // [1,0,3,2] = 0xB1
    return __int_as_float(__builtin_amdgcn_mov_dpp(__float_as_int(a), 0xB1, 0xF, 0xF, true));
}
__device__ __forceinline__ float qp_xor2(float a) {   // [2,3,0,1] = 0x4E
    return __int_as_float(__builtin_amdgcn_mov_dpp(__float_as_int(a), 0x4E, 0xF, 0xF, true));
}

__global__ __launch_bounds__(256, 2) void dlgn_v16_kernel(
    const float* __restrict__ x,
    const float* __restrict__ W1,
    const float* __restrict__ W2,
    const float* __restrict__ W3,
    const float* __restrict__ V,
    float* __restrict__ out)
{
    __shared__ float xlds[8 * 160];   //  5120 B: kc-chunk stride 20
    __shared__ float Gs[8][100];      //  3200 B
    __shared__ float Plds[2560];      // 10240 B: per-thread stride 10

    const int t  = threadIdx.x;
    const int b0 = blockIdx.x * 8;

    // ---- Stage x tile: 1 float4/thread, coalesced; kc-skewed layout ----
    {
        const int r    = t >> 5;
        const int col4 = t & 31;
        const float4 xv = ((const float4*)(x + (size_t)(b0 + r) * 128))[col4];
        const int skc = col4 >> 2, sc = col4 & 3;
        *(float4*)&xlds[r * 160 + skc * 20 + sc * 4] = xv;
    }

    // ---- W chunks -> 48 registers (global, L2-resident) ----
    const int fl = t >> 3;   // feature-lane 0..31
    const int kc = t & 7;    // k-chunk 0..7
    float4 w1c[4], w2c[4], w3c[4];
    {
        const float4* W1r = (const float4*)(W1 + fl * 128 + kc * 16);
        const float4* W2r = (const float4*)(W2 + fl * 128 + kc * 16);
        const float4* W3r = (const float4*)(W3 + fl * 128 + kc * 16);
#pragma unroll
        for (int c = 0; c < 4; ++c) {
            w1c[c] = W1r[c]; w2c[c] = W2r[c]; w3c[c] = W3r[c];
        }
    }
    __syncthreads();   // xlds ready

    // ---- Phase 1: 8 rows x 3 matrices, packed k-eighth partial dots ----
    v2f acc2[3][8];
#pragma unroll
    for (int m = 0; m < 3; ++m)
#pragma unroll
        for (int r = 0; r < 8; ++r) acc2[m][r] = (v2f){0.f, 0.f};

#pragma unroll
    for (int r = 0; r < 8; ++r) {
        float4 xc[4];
#pragma unroll
        for (int c = 0; c < 4; ++c)
            xc[c] = *(const float4*)&xlds[r * 160 + kc * 20 + c * 4];
#pragma unroll
        for (int c = 0; c < 4; ++c) {
            const v2f xlo = (v2f){xc[c].x, xc[c].y};
            const v2f xhi = (v2f){xc[c].z, xc[c].w};
            acc2[0][r] = __builtin_elementwise_fma((v2f){w1c[c].x, w1c[c].y}, xlo, acc2[0][r]);
            acc2[0][r] = __builtin_elementwise_fma((v2f){w1c[c].z, w1c[c].w}, xhi, acc2[0][r]);
            acc2[1][r] = __builtin_elementwise_fma((v2f){w2c[c].x, w2c[c].y}, xlo, acc2[1][r]);
            acc2[1][r] = __builtin_elementwise_fma((v2f){w2c[c].z, w2c[c].w}, xhi, acc2[1][r]);
            acc2[2][r] = __builtin_elementwise_fma((v2f){w3c[c].x, w3c[c].y}, xlo, acc2[2][r]);
            acc2[2][r] = __builtin_elementwise_fma((v2f){w3c[c].z, w3c[c].w}, xhi, acc2[2][r]);
        }
    }

    // ---- Issue V loads now (W regs dead); complete under combine + barrier ----
    const float4* V4 = (const float4*)V;   // f4 idx = i*256 + t
    float4 v[32];
#pragma unroll
    for (int i = 0; i < 32; ++i) v[i] = V4[i * 256 + t];

    // ---- Combine k-eighths: horizontal add, DPP xor1/xor2 + shfl xor4; sigmoid -> Gs ----
#pragma unroll
    for (int m = 0; m < 3; ++m) {
        float sel = 0.f;
#pragma unroll
        for (int r = 0; r < 8; ++r) {
            float a = acc2[m][r].x + acc2[m][r].y;
            a += qp_xor1(a);
            a += qp_xor2(a);
            a += __shfl_xor(a, 4);
            if (kc == r) sel = a;      // static select chain
        }
        Gs[kc][32 * m + fl] = 1.0f / (1.0f + __expf(-BETA * sel));
    }
    __syncthreads();

    // ---- Phase 2: thread = (j = t>>3, c2 = t&7); g1 via readlane; packed u ----
    const int j  = t >> 3;   // [0,32)
    const int c2 = t & 7;    // [0,8)

    float p8[8];
#pragma unroll
    for (int b = 0; b < 8; ++b) {
        const float  ga  = Gs[b][t & 31];               // lane l holds g1[b][l&31]
        const float  g2s = Gs[b][32 + j];
        const float4 g3r = *(const float4*)&Gs[b][64 + c2 * 4];

        v2f u2a = (v2f){0.f, 0.f};   // {x,y} accumulator
        v2f u2b = (v2f){0.f, 0.f};   // {z,w} accumulator
#pragma unroll
        for (int i = 0; i < 32; ++i) {
            const float g1i = __int_as_float(
                __builtin_amdgcn_readlane(__float_as_int(ga), i));   // SGPR
            const v2f g1v = (v2f){g1i, g1i};
            u2a = __builtin_elementwise_fma(g1v, (v2f){v[i].x, v[i].y}, u2a);
            u2b = __builtin_elementwise_fma(g1v, (v2f){v[i].z, v[i].w}, u2b);
        }
        float s = u2a.x * g3r.x;
        s = fmaf(u2a.y, g3r.y, s);
        s = fmaf(u2b.x, g3r.z, s);
        s = fmaf(u2b.y, g3r.w, s);
        p8[b] = s * g2s;
    }

    // ---- Deferred reduction: 2 packed b128 writes, barrier, one final pass ----
    *(float4*)&Plds[t * 10]     = make_float4(p8[0], p8[1], p8[2], p8[3]);
    *(float4*)&Plds[t * 10 + 4] = make_float4(p8[4], p8[5], p8[6], p8[7]);
    __syncthreads();

    {
        const int fb2 = t >> 5;   // b index 0..7
        const int pt  = t & 31;   // partial index
        float s = 0.f;
#pragma unroll
        for (int s8 = 0; s8 < 8; ++s8)
            s += Plds[(pt + s8 * 32) * 10 + fb2];
        s += __shfl_xor(s, 1);
        s += __shfl_xor(s, 2);
        s += __shfl_xor(s, 4);
        s += __shfl_xor(s, 8);
        s += __shfl_xor(s, 16);
        if (pt == 0) out[b0 + fb2] = s;
    }
}

extern "C" void kernel_launch(void* const* d_in, const int* in_sizes, int n_in,
                              void* d_out, int out_size, void* d_ws, size_t ws_size,
                              hipStream_t stream) {
    const float* x  = (const float*)d_in[0];
    const float* W1 = (const float*)d_in[1];
    const float* W2 = (const float*)d_in[2];
    const float* W3 = (const float*)d_in[3];
    const float* V  = (const float*)d_in[4];
    float* out = (float*)d_out;

    dlgn_v16_kernel<<<dim3(512), dim3(256), 0, stream>>>(x, W1, W2, W3, V, out);
}